// Round 2
// baseline (462.714 us; speedup 1.0000x reference)
//
#include <hip/hip_runtime.h>
#include <math.h>

#define NEMB 200000
#define DD   128
#define MM   200
#define KTOP 32
#define BB   1024
#define FEW  5
#define DM   256
#define DF   512
#define HH   512

__device__ __forceinline__ float sigf(float x) { return 1.0f / (1.0f + expf(-x)); }

// ---------------------------------------------------------------------------
// K1: neighbor encoder. One block per (row, half). 2058 blocks, 256 threads.
// Thread-per-neighbor sims (32 independent float4 loads each, no shuffle
// chains). Also writes yq = qn2 + se_b2 (SE2 residual+bias pre-init).
// ---------------------------------------------------------------------------
__global__ __launch_bounds__(256) void neighbor_kernel(
    const int* __restrict__ query, const int* __restrict__ support,
    const int* __restrict__ q_l_conn, const int* __restrict__ q_r_conn,
    const int* __restrict__ s_l_conn, const int* __restrict__ s_r_conn,
    const float* __restrict__ emb,
    const float* __restrict__ gcn_W, const float* __restrict__ gcn_bias,
    const float* __restrict__ gcn_b, const float* __restrict__ se_b2,
    float* __restrict__ qn2, float* __restrict__ yq)
{
    __shared__ float cent[128];
    __shared__ float sims[MM];
    __shared__ int   cids[MM];
    __shared__ int   selr[KTOP];
    __shared__ int   sele[KTOP];
    __shared__ float avg[256];
    __shared__ float red[256];
    __shared__ int   nsel;

    const int t   = threadIdx.x;
    const int blk = blockIdx.x;

    const int* conn; int eid, row_out, half;
    if (blk < BB)            { conn = q_l_conn + blk * MM * 2;                eid = query[blk * 2 + 0];              row_out = blk;    half = 0; }
    else if (blk < 2 * BB)   { int b = blk - BB;        conn = q_r_conn + b * MM * 2; eid = query[b * 2 + 1];       row_out = b;      half = 1; }
    else if (blk < 2 * BB + FEW) { int r = blk - 2 * BB;   conn = s_l_conn + r * MM * 2; eid = support[r * 2 + 0];  row_out = BB + r; half = 0; }
    else                     { int r = blk - 2 * BB - FEW; conn = s_r_conn + r * MM * 2; eid = support[r * 2 + 1];  row_out = BB + r; half = 1; }

    if (t < 32)  ((float4*)cent)[t] = ((const float4*)(emb + (size_t)eid * DD))[t];
    if (t < MM)  cids[t] = conn[t * 2 + 1];
    if (t == 0)  nsel = 0;
    __syncthreads();

    // sims: one thread per neighbor, 32 independent float4 loads
    if (t < MM) {
        const float4* er = (const float4*)(emb + (size_t)cids[t] * DD);
        const float4* cc = (const float4*)cent;
        float num = 0.f, sq = 0.f, csq = 0.f;
        #pragma unroll 8
        for (int i = 0; i < 32; ++i) {
            float4 e = er[i];
            float4 c = cc[i];   // same-address LDS broadcast: conflict-free
            num += c.x * e.x + c.y * e.y + c.z * e.z + c.w * e.w;
            sq  += e.x * e.x + e.y * e.y + e.z * e.z + e.w * e.w;
            csq += c.x * c.x + c.y * c.y + c.z * c.z + c.w * c.w;
        }
        sims[t] = num / fmaxf(sqrtf(csq) * sqrtf(sq), 1e-8f);
    }
    __syncthreads();

    // top-K by rank; tie-break lower index (lax.top_k semantics)
    if (t < MM) {
        float st = sims[t];
        int cnt = 0;
        for (int j = 0; j < MM; ++j) {
            float sj = sims[j];
            cnt += (sj > st) || (sj == st && j < t);
        }
        if (cnt < KTOP) {
            int p = atomicAdd(&nsel, 1);
            selr[p] = conn[t * 2 + 0];
            sele[p] = cids[t];
        }
    }
    __syncthreads();

    // mean over selected K of [rel; ent]
    {
        float acc = 0.0f;
        const int dloc = t & 127;
        const bool is_ent = (t >= 128);
        for (int s = 0; s < KTOP; ++s) {
            int rid = is_ent ? sele[s] : selr[s];
            acc += emb[(size_t)rid * DD + dloc];
        }
        avg[t] = acc * (1.0f / KTOP);
    }
    __syncthreads();

    // out[d] = tanh( gcn_W[d,:] . avg + gcn_bias[d] + gcn_b[d] )
    {
        const int d   = t & 127;
        const int c0i = (t >> 7) * 128;
        float acc = 0.0f;
        const float* wrow = gcn_W + d * 256 + c0i;
        #pragma unroll 4
        for (int c = 0; c < 128; ++c) acc += wrow[c] * avg[c0i + c];
        red[t] = acc;
    }
    __syncthreads();
    if (t < 128) {
        float o = tanhf(red[t] + red[t + 128] + gcn_bias[t] + gcn_b[t]);
        int idx = row_out * 256 + half * 128 + t;
        qn2[idx] = o;
        yq[idx]  = o + se_b2[half * 128 + t];   // SE2 residual + bias pre-init
    }
}

// ---------------------------------------------------------------------------
// Split-K fp32 GEMM: C[M,N] += A[M,K-slice] @ W[N',K-slice]^T via atomicAdd.
// RELU_A applies relu to A on load (SE2 consumes relu(h1)).
// GMAP remaps output col n -> W row ((n>>8)<<9)|(n&255) (LSTM gate compaction:
// only the first 256 of each 512-wide gate chunk are consumed).
// Block tile 64x64, K-tile 16, 256 threads, 4x4 microtile.
// ---------------------------------------------------------------------------
template <bool RELU_A, bool GMAP>
__global__ __launch_bounds__(256) void gemm_splitk(
    const float* __restrict__ A, const float* __restrict__ W,
    float* __restrict__ C, int M_, int N_, int K_, int KS)
{
    __shared__ float As[16][68];
    __shared__ float Ws[16][68];
    const int t   = threadIdx.x;
    const int bm  = blockIdx.y * 64, bn = blockIdx.x * 64;
    const int k0b = blockIdx.z * KS, k0e = k0b + KS;
    const int tx = t & 15, ty = t >> 4;
    const int lrow = t >> 2, lk4 = (t & 3) * 4;

    int wrow = bn + lrow;
    if (GMAP) wrow = ((wrow >> 8) << 9) | (wrow & 255);
    const float* Ap = A + (size_t)(bm + lrow) * K_ + lk4;
    const float* Wp = W + (size_t)wrow * K_ + lk4;

    float acc[4][4] = {};
    for (int k0 = k0b; k0 < k0e; k0 += 16) {
        float4 av = *(const float4*)(Ap + k0);
        float4 wv = *(const float4*)(Wp + k0);
        if (RELU_A) {
            av.x = fmaxf(av.x, 0.f); av.y = fmaxf(av.y, 0.f);
            av.z = fmaxf(av.z, 0.f); av.w = fmaxf(av.w, 0.f);
        }
        __syncthreads();
        As[lk4 + 0][lrow] = av.x; As[lk4 + 1][lrow] = av.y;
        As[lk4 + 2][lrow] = av.z; As[lk4 + 3][lrow] = av.w;
        Ws[lk4 + 0][lrow] = wv.x; Ws[lk4 + 1][lrow] = wv.y;
        Ws[lk4 + 2][lrow] = wv.z; Ws[lk4 + 3][lrow] = wv.w;
        __syncthreads();
        #pragma unroll
        for (int kk = 0; kk < 16; ++kk) {
            float4 a = *(const float4*)&As[kk][ty * 4];
            float4 b = *(const float4*)&Ws[kk][tx * 4];
            acc[0][0] += a.x * b.x; acc[0][1] += a.x * b.y; acc[0][2] += a.x * b.z; acc[0][3] += a.x * b.w;
            acc[1][0] += a.y * b.x; acc[1][1] += a.y * b.y; acc[1][2] += a.y * b.z; acc[1][3] += a.y * b.w;
            acc[2][0] += a.z * b.x; acc[2][1] += a.z * b.y; acc[2][2] += a.z * b.z; acc[2][3] += a.z * b.w;
            acc[3][0] += a.w * b.x; acc[3][1] += a.w * b.y; acc[3][2] += a.w * b.z; acc[3][3] += a.w * b.w;
        }
    }

    const int n0 = bn + tx * 4;
    #pragma unroll
    for (int i = 0; i < 4; ++i) {
        float* cp = C + (size_t)(bm + ty * 4 + i) * N_ + n0;
        atomicAdd(cp + 0, acc[i][0]);
        atomicAdd(cp + 1, acc[i][1]);
        atomicAdd(cp + 2, acc[i][2]);
        atomicAdd(cp + 3, acc[i][3]);
    }
}

// ---------------------------------------------------------------------------
// init: h1q = b1[n] (1088x512), gates = b_ih[nb]+b_hh[nb] (1024x1024 compact)
// ---------------------------------------------------------------------------
__global__ __launch_bounds__(256) void init_pre_kernel(
    const float* __restrict__ b1, const float* __restrict__ b_ih,
    const float* __restrict__ b_hh, float* __restrict__ h1q,
    float* __restrict__ gates)
{
    int i = blockIdx.x * 256 + threadIdx.x;
    if (i < 1088 * 512) {
        h1q[i] = b1[i & 511];
    } else {
        int j = i - 1088 * 512;
        int n = j & 1023;
        int nb = ((n >> 8) << 9) | (n & 255);
        gates[j] = b_ih[nb] + b_hh[nb];
    }
}

// ---------------------------------------------------------------------------
// LayerNorm per row (256 dims) — shuffle reduce, one barrier
// ---------------------------------------------------------------------------
__global__ __launch_bounds__(256) void ln_kernel(
    const float* __restrict__ y, const float* __restrict__ g,
    const float* __restrict__ beta, float* __restrict__ out)
{
    __shared__ float rs[4], rq[4];
    const int row = blockIdx.x, t = threadIdx.x;
    const int lane = t & 63, wave = t >> 6;
    float v = y[row * 256 + t];
    float s = v, q = v * v;
    #pragma unroll
    for (int i = 32; i >= 1; i >>= 1) { s += __shfl_xor(s, i, 64); q += __shfl_xor(q, i, 64); }
    if (lane == 0) { rs[wave] = s; rq[wave] = q; }
    __syncthreads();
    float tot  = rs[0] + rs[1] + rs[2] + rs[3];
    float totq = rq[0] + rq[1] + rq[2] + rq[3];
    float mu  = tot * (1.0f / 256.0f);
    float var = fmaxf(totq * (1.0f / 256.0f) - mu * mu, 0.0f);
    out[row * 256 + t] = g[t] * (v - mu) / sqrtf(var + 1e-5f) + beta[t];
}

// ---------------------------------------------------------------------------
// support_g = mean over 5 LN'd support rows; sgn = l2norm(sg0)
// ---------------------------------------------------------------------------
__global__ __launch_bounds__(256) void support_mean_kernel(
    const float* __restrict__ qg2, float* __restrict__ sg0, float* __restrict__ sgn)
{
    __shared__ float rq[4];
    const int t = threadIdx.x;
    const int lane = t & 63, wave = t >> 6;
    float s = 0.0f;
    #pragma unroll
    for (int r = 0; r < FEW; ++r) s += qg2[(BB + r) * 256 + t];
    s *= (1.0f / FEW);
    sg0[t] = s;
    float q = s * s;
    #pragma unroll
    for (int i = 32; i >= 1; i >>= 1) q += __shfl_xor(q, i, 64);
    if (lane == 0) rq[wave] = q;
    __syncthreads();
    float nrm = sqrtf(rq[0] + rq[1] + rq[2] + rq[3]);
    sgn[t] = s / fmaxf(nrm, 1e-12f);
}

// gates compact layout: [0:256)=i [256:512)=f [512:768)=g [768:1024)=o
__global__ __launch_bounds__(256) void lstm_step1_kernel(
    const float* __restrict__ gates, const float* __restrict__ qg,
    const float* __restrict__ sg0, float* __restrict__ c1, float* __restrict__ hr)
{
    const int row = blockIdx.x, t = threadIdx.x;
    const float* gr = gates + row * 1024;
    float iv = gr[t], gv = gr[512 + t], ov = gr[768 + t];
    float cv = sigf(iv) * tanhf(gv);          // c0 = 0 => f-term drops
    c1[row * 256 + t] = cv;
    float hf = sigf(ov) * tanhf(cv);
    hr[row * 512 + t]       = qg[row * 256 + t] + hf;  // h1
    hr[row * 512 + 256 + t] = sg0[t];                  // r (softmax over 1 => attn==1)
}

__global__ __launch_bounds__(256) void lstm_step2_kernel(
    const float* __restrict__ gates, const float* __restrict__ c1,
    const float* __restrict__ qg, const float* __restrict__ sgn,
    float* __restrict__ outv)
{
    __shared__ float rn[4], rd[4];
    const int row = blockIdx.x, t = threadIdx.x;
    const int lane = t & 63, wave = t >> 6;
    const float* gr = gates + row * 1024;
    float iv = gr[t], fv = gr[256 + t], gv = gr[512 + t], ov = gr[768 + t];
    float cv = sigf(fv) * c1[row * 256 + t] + sigf(iv) * tanhf(gv);
    float h2 = qg[row * 256 + t] + sigf(ov) * tanhf(cv);
    float nn = h2 * h2, dd = h2 * sgn[t];
    #pragma unroll
    for (int i = 32; i >= 1; i >>= 1) { nn += __shfl_xor(nn, i, 64); dd += __shfl_xor(dd, i, 64); }
    if (lane == 0) { rn[wave] = nn; rd[wave] = dd; }
    __syncthreads();
    if (t == 0) {
        float n2 = rn[0] + rn[1] + rn[2] + rn[3];
        float dt = rd[0] + rd[1] + rd[2] + rd[3];
        outv[row] = dt / fmaxf(sqrtf(n2), 1e-12f);
    }
}

extern "C" void kernel_launch(void* const* d_in, const int* in_sizes, int n_in,
                              void* d_out, int out_size, void* d_ws, size_t ws_size,
                              hipStream_t stream)
{
    const int*   query    = (const int*)d_in[0];
    const int*   support  = (const int*)d_in[1];
    const int*   q_l_conn = (const int*)d_in[2];
    const int*   q_r_conn = (const int*)d_in[4];
    const int*   s_l_conn = (const int*)d_in[6];
    const int*   s_r_conn = (const int*)d_in[8];
    const float* emb      = (const float*)d_in[10];
    const float* gcn_W    = (const float*)d_in[11];
    const float* gcn_bias = (const float*)d_in[12];
    const float* gcn_b    = (const float*)d_in[13];
    const float* se_w1    = (const float*)d_in[14];
    const float* se_b1    = (const float*)d_in[15];
    const float* se_w2    = (const float*)d_in[16];
    const float* se_b2    = (const float*)d_in[17];
    const float* ln_g     = (const float*)d_in[18];
    const float* ln_b     = (const float*)d_in[19];
    const float* W_ih     = (const float*)d_in[20];
    const float* W_hh     = (const float*)d_in[21];
    const float* b_ih     = (const float*)d_in[22];
    const float* b_hh     = (const float*)d_in[23];
    float* out = (float*)d_out;

    float* ws    = (float*)d_ws;
    float* qn2   = ws;                    // 1088*256
    float* h1q   = qn2   + 1088 * 256;    // 1088*512
    float* yq    = h1q   + 1088 * 512;    // 1088*256
    float* qg2   = yq    + 1088 * 256;    // 1088*256
    float* sg0   = qg2   + 1088 * 256;    // 256
    float* sgn   = sg0   + 256;           // 256
    float* gates = sgn   + 256;           // 1024*1024
    float* c1    = gates + 1024 * 1024;   // 1024*256
    float* hr    = c1    + 1024 * 256;    // 1024*512

    // 0. bias pre-inits (independent of everything)
    init_pre_kernel<<<(1088 * 512 + 1024 * 1024) / 256, 256, 0, stream>>>(
        se_b1, b_ih, b_hh, h1q, gates);

    // 1. neighbor encoder -> qn2 (+ yq = qn2 + se_b2)
    neighbor_kernel<<<2 * BB + 2 * FEW, 256, 0, stream>>>(
        query, support, q_l_conn, q_r_conn, s_l_conn, s_r_conn,
        emb, gcn_W, gcn_bias, gcn_b, se_b2, qn2, yq);

    // 2. SE GEMM1 (split-K=2): h1q += qn2 @ w1^T
    gemm_splitk<false, false><<<dim3(8, 17, 2), 256, 0, stream>>>(
        qn2, se_w1, h1q, 1088, 512, 256, 128);

    // 3. SE GEMM2 (split-K=4, relu on A): yq += relu(h1q) @ w2^T
    gemm_splitk<true, false><<<dim3(4, 17, 4), 256, 0, stream>>>(
        h1q, se_w2, yq, 1088, 256, 512, 128);

    // 4. LayerNorm -> qg2
    ln_kernel<<<1029, 256, 0, stream>>>(yq, ln_g, ln_b, qg2);

    // 5. support_g mean + l2norm
    support_mean_kernel<<<1, 256, 0, stream>>>(qg2, sg0, sgn);

    // 6. gates += qg2 @ W_ih'^T (split-K=2, gate-compacted N=1024)
    gemm_splitk<false, true><<<dim3(16, 16, 2), 256, 0, stream>>>(
        qg2, W_ih, gates, 1024, 1024, 256, 128);

    // 7. LSTM step 1 (c0=0, h_r0=0)
    lstm_step1_kernel<<<1024, 256, 0, stream>>>(gates, qg2, sg0, c1, hr);

    // 8. gates += hr @ W_hh'^T (split-K=4, in-place on gates_base)
    gemm_splitk<false, true><<<dim3(16, 16, 4), 256, 0, stream>>>(
        hr, W_hh, gates, 1024, 1024, 512, 128);

    // 9. LSTM step 2 + l2norm + dot(support_gn)
    lstm_step2_kernel<<<1024, 256, 0, stream>>>(gates, c1, qg2, sgn, out);
}

// Round 3
// 406.067 us; speedup vs baseline: 1.1395x; 1.1395x over previous
//
#include <hip/hip_runtime.h>
#include <math.h>

#define NEMB 200000
#define DD   128
#define MM   200
#define KTOP 32
#define BB   1024
#define FEW  5
#define DM   256
#define DF   512
#define HH   512

__device__ __forceinline__ float sigf(float x) { return 1.0f / (1.0f + expf(-x)); }

// ---------------------------------------------------------------------------
// K1: neighbor encoder. One block per (row, half). 2058 blocks, 256 threads.
// Sims phase: 4 lanes per neighbor row -> each wave load instruction touches
// 16 distinct rows x 64 B contiguous = 16 cache lines (vs 64 for
// thread-per-row). Center fragment in registers; width-4 shuffle reduce.
// ---------------------------------------------------------------------------
__global__ __launch_bounds__(256) void neighbor_kernel(
    const int* __restrict__ query, const int* __restrict__ support,
    const int* __restrict__ q_l_conn, const int* __restrict__ q_r_conn,
    const int* __restrict__ s_l_conn, const int* __restrict__ s_r_conn,
    const float* __restrict__ emb,
    const float* __restrict__ gcn_W, const float* __restrict__ gcn_bias,
    const float* __restrict__ gcn_b, float* __restrict__ qn2)
{
    __shared__ float cent[128];
    __shared__ float sims[MM];
    __shared__ int   cids[MM];
    __shared__ int   selr[KTOP];
    __shared__ int   sele[KTOP];
    __shared__ float avg[256];
    __shared__ float partial[512];
    __shared__ float red[256];
    __shared__ int   nsel;

    const int t   = threadIdx.x;
    const int blk = blockIdx.x;

    const int* conn; int eid, row_out, half;
    if (blk < BB)            { conn = q_l_conn + blk * MM * 2;                eid = query[blk * 2 + 0];              row_out = blk;    half = 0; }
    else if (blk < 2 * BB)   { int b = blk - BB;        conn = q_r_conn + b * MM * 2; eid = query[b * 2 + 1];       row_out = b;      half = 1; }
    else if (blk < 2 * BB + FEW) { int r = blk - 2 * BB;   conn = s_l_conn + r * MM * 2; eid = support[r * 2 + 0];  row_out = BB + r; half = 0; }
    else                     { int r = blk - 2 * BB - FEW; conn = s_r_conn + r * MM * 2; eid = support[r * 2 + 1];  row_out = BB + r; half = 1; }

    if (t < 32)  ((float4*)cent)[t] = ((const float4*)(emb + (size_t)eid * DD))[t];
    if (t < MM)  cids[t] = conn[t * 2 + 1];
    if (t == 0)  nsel = 0;
    __syncthreads();

    // ---- sims: 4-lane groups, one row per group per round ----
    const int l4 = t & 3, g = t >> 2;   // 64 groups
    float4 cr[8];
    #pragma unroll
    for (int i = 0; i < 8; ++i) cr[i] = ((const float4*)cent)[i * 4 + l4];
    float csq = 0.f;
    #pragma unroll
    for (int i = 0; i < 8; ++i)
        csq += cr[i].x * cr[i].x + cr[i].y * cr[i].y + cr[i].z * cr[i].z + cr[i].w * cr[i].w;
    csq += __shfl_xor(csq, 1, 4);
    csq += __shfl_xor(csq, 2, 4);
    const float cn = sqrtf(csq);

    #pragma unroll
    for (int r = 0; r < 4; ++r) {
        int j = g + (r << 6);
        if (j < MM) {
            const float4* er = (const float4*)(emb + (size_t)cids[j] * DD) + l4;
            float num = 0.f, sq = 0.f;
            #pragma unroll
            for (int i = 0; i < 8; ++i) {
                float4 e = er[i * 4];
                num += cr[i].x * e.x + cr[i].y * e.y + cr[i].z * e.z + cr[i].w * e.w;
                sq  += e.x * e.x + e.y * e.y + e.z * e.z + e.w * e.w;
            }
            num += __shfl_xor(num, 1, 4); num += __shfl_xor(num, 2, 4);
            sq  += __shfl_xor(sq , 1, 4); sq  += __shfl_xor(sq , 2, 4);
            if (l4 == 0) sims[j] = num / fmaxf(cn * sqrtf(sq), 1e-8f);
        }
    }
    __syncthreads();

    // ---- top-K by rank; tie-break lower index (lax.top_k semantics) ----
    if (t < MM) {
        float st = sims[t];
        int cnt = 0;
        for (int j = 0; j < MM; ++j) {
            float sj = sims[j];
            cnt += (sj > st) || (sj == st && j < t);
        }
        if (cnt < KTOP) {
            int p = atomicAdd(&nsel, 1);
            selr[p] = conn[t * 2 + 0];
            sele[p] = cids[t];
        }
    }
    __syncthreads();

    // ---- mean over selected K of [rel; ent], float2 coalesced ----
    {
        const int slot = t & 127;          // float2 slot: <64 rel dims, >=64 ent dims
        const int hpar = t >> 7;           // row-parity split
        const bool isEnt = slot >= 64;
        float2 acc = make_float2(0.f, 0.f);
        for (int s = hpar; s < KTOP; s += 2) {
            int rid = isEnt ? sele[s] : selr[s];
            float2 v = ((const float2*)(emb + (size_t)rid * DD))[slot & 63];
            acc.x += v.x; acc.y += v.y;
        }
        ((float2*)partial)[t] = acc;
    }
    __syncthreads();
    if (t < 128) {
        float2 a = ((float2*)partial)[t];
        float2 b = ((float2*)partial)[t + 128];
        ((float2*)avg)[t] = make_float2((a.x + b.x) * (1.0f / KTOP),
                                        (a.y + b.y) * (1.0f / KTOP));
    }
    __syncthreads();

    // ---- out[d] = tanh( gcn_W[d,:] . avg + gcn_bias[d] + gcn_b[d] ) ----
    {
        const int d   = t & 127;
        const int c0i = (t >> 7) * 128;
        float acc = 0.0f;
        const float* wrow = gcn_W + d * 256 + c0i;
        #pragma unroll 4
        for (int c = 0; c < 128; ++c) acc += wrow[c] * avg[c0i + c];
        red[t] = acc;
    }
    __syncthreads();
    if (t < 128) {
        float o = red[t] + red[t + 128] + gcn_bias[t] + gcn_b[t];
        qn2[row_out * 256 + half * 128 + t] = tanhf(o);
    }
}

// ---------------------------------------------------------------------------
// Generic fp32 GEMM: C[M,N] = A[M,K] @ W[N',K]^T (+bias)(+add)(relu)
// GMAP remaps output col n -> W row ((n>>8)<<9)|(n&255)  (gate compaction)
// Block tile 64x64, K-tile 16, 256 threads, 4x4 microtile.
// ---------------------------------------------------------------------------
template <bool RELU, bool HAS_ADD, bool GMAP>
__global__ __launch_bounds__(256) void gemm_nt(
    const float* __restrict__ A, const float* __restrict__ W,
    const float* __restrict__ bias, const float* __restrict__ add,
    float* __restrict__ C, int M_, int N_, int K_)
{
    __shared__ float As[16][68];
    __shared__ float Ws[16][68];
    const int t  = threadIdx.x;
    const int bm = blockIdx.y * 64, bn = blockIdx.x * 64;
    const int tx = t & 15, ty = t >> 4;
    const int lrow = t >> 2, lk4 = (t & 3) * 4;

    int wrow = bn + lrow;
    if (GMAP) wrow = ((wrow >> 8) << 9) | (wrow & 255);
    const float* Ap = A + (size_t)(bm + lrow) * K_ + lk4;
    const float* Wp = W + (size_t)wrow * K_ + lk4;

    float acc[4][4] = {};
    for (int k0 = 0; k0 < K_; k0 += 16) {
        float4 av = *(const float4*)(Ap + k0);
        float4 wv = *(const float4*)(Wp + k0);
        __syncthreads();
        As[lk4 + 0][lrow] = av.x; As[lk4 + 1][lrow] = av.y;
        As[lk4 + 2][lrow] = av.z; As[lk4 + 3][lrow] = av.w;
        Ws[lk4 + 0][lrow] = wv.x; Ws[lk4 + 1][lrow] = wv.y;
        Ws[lk4 + 2][lrow] = wv.z; Ws[lk4 + 3][lrow] = wv.w;
        __syncthreads();
        #pragma unroll
        for (int kk = 0; kk < 16; ++kk) {
            float4 a = *(const float4*)&As[kk][ty * 4];
            float4 b = *(const float4*)&Ws[kk][tx * 4];
            acc[0][0] += a.x * b.x; acc[0][1] += a.x * b.y; acc[0][2] += a.x * b.z; acc[0][3] += a.x * b.w;
            acc[1][0] += a.y * b.x; acc[1][1] += a.y * b.y; acc[1][2] += a.y * b.z; acc[1][3] += a.y * b.w;
            acc[2][0] += a.z * b.x; acc[2][1] += a.z * b.y; acc[2][2] += a.z * b.z; acc[2][3] += a.z * b.w;
            acc[3][0] += a.w * b.x; acc[3][1] += a.w * b.y; acc[3][2] += a.w * b.z; acc[3][3] += a.w * b.w;
        }
    }

    const int n0 = bn + tx * 4;
    float4 bv = make_float4(0.f, 0.f, 0.f, 0.f);
    if (bias) {
        int nb = GMAP ? (((n0 >> 8) << 9) | (n0 & 255)) : n0;
        bv = *(const float4*)(bias + nb);
    }
    #pragma unroll
    for (int i = 0; i < 4; ++i) {
        int m = bm + ty * 4 + i;
        float4 v = make_float4(acc[i][0] + bv.x, acc[i][1] + bv.y,
                               acc[i][2] + bv.z, acc[i][3] + bv.w);
        if (HAS_ADD) {
            float4 ad = *(const float4*)(add + (size_t)m * N_ + n0);
            v.x += ad.x; v.y += ad.y; v.z += ad.z; v.w += ad.w;
        }
        if (RELU) {
            v.x = fmaxf(v.x, 0.f); v.y = fmaxf(v.y, 0.f);
            v.z = fmaxf(v.z, 0.f); v.w = fmaxf(v.w, 0.f);
        }
        *(float4*)(C + (size_t)m * N_ + n0) = v;
    }
}

// ---------------------------------------------------------------------------
// LayerNorm per row (256 dims) — shuffle reduce, one barrier
// ---------------------------------------------------------------------------
__global__ __launch_bounds__(256) void ln_kernel(
    const float* __restrict__ y, const float* __restrict__ g,
    const float* __restrict__ beta, float* __restrict__ out)
{
    __shared__ float rs[4], rq[4];
    const int row = blockIdx.x, t = threadIdx.x;
    const int lane = t & 63, wave = t >> 6;
    float v = y[row * 256 + t];
    float s = v, q = v * v;
    #pragma unroll
    for (int i = 32; i >= 1; i >>= 1) { s += __shfl_xor(s, i, 64); q += __shfl_xor(q, i, 64); }
    if (lane == 0) { rs[wave] = s; rq[wave] = q; }
    __syncthreads();
    float tot  = rs[0] + rs[1] + rs[2] + rs[3];
    float totq = rq[0] + rq[1] + rq[2] + rq[3];
    float mu  = tot * (1.0f / 256.0f);
    float var = fmaxf(totq * (1.0f / 256.0f) - mu * mu, 0.0f);
    out[row * 256 + t] = g[t] * (v - mu) / sqrtf(var + 1e-5f) + beta[t];
}

// ---------------------------------------------------------------------------
// support_g = mean over 5 LN'd support rows; sgn = l2norm(sg0)
// ---------------------------------------------------------------------------
__global__ __launch_bounds__(256) void support_mean_kernel(
    const float* __restrict__ qg2, float* __restrict__ sg0, float* __restrict__ sgn)
{
    __shared__ float rq[4];
    const int t = threadIdx.x;
    const int lane = t & 63, wave = t >> 6;
    float s = 0.0f;
    #pragma unroll
    for (int r = 0; r < FEW; ++r) s += qg2[(BB + r) * 256 + t];
    s *= (1.0f / FEW);
    sg0[t] = s;
    float q = s * s;
    #pragma unroll
    for (int i = 32; i >= 1; i >>= 1) q += __shfl_xor(q, i, 64);
    if (lane == 0) rq[wave] = q;
    __syncthreads();
    float nrm = sqrtf(rq[0] + rq[1] + rq[2] + rq[3]);
    sgn[t] = s / fmaxf(nrm, 1e-12f);
}

__global__ __launch_bounds__(256) void bsum_kernel(
    const float* __restrict__ a, const float* __restrict__ b, float* __restrict__ o)
{
    int i = blockIdx.x * 256 + threadIdx.x;
    o[i] = a[i] + b[i];
}

// gates compact layout: [0:256)=i [256:512)=f [512:768)=g [768:1024)=o
__global__ __launch_bounds__(256) void lstm_step1_kernel(
    const float* __restrict__ gates, const float* __restrict__ qg,
    const float* __restrict__ sg0, float* __restrict__ c1, float* __restrict__ hr)
{
    const int row = blockIdx.x, t = threadIdx.x;
    const float* gr = gates + row * 1024;
    float iv = gr[t], gv = gr[512 + t], ov = gr[768 + t];
    float cv = sigf(iv) * tanhf(gv);          // c0 = 0 => f-term drops
    c1[row * 256 + t] = cv;
    float hf = sigf(ov) * tanhf(cv);
    hr[row * 512 + t]       = qg[row * 256 + t] + hf;  // h1
    hr[row * 512 + 256 + t] = sg0[t];                  // r (softmax over 1 => attn==1)
}

__global__ __launch_bounds__(256) void lstm_step2_kernel(
    const float* __restrict__ gates, const float* __restrict__ c1,
    const float* __restrict__ qg, const float* __restrict__ sgn,
    float* __restrict__ outv)
{
    __shared__ float rn[4], rd[4];
    const int row = blockIdx.x, t = threadIdx.x;
    const int lane = t & 63, wave = t >> 6;
    const float* gr = gates + row * 1024;
    float iv = gr[t], fv = gr[256 + t], gv = gr[512 + t], ov = gr[768 + t];
    float cv = sigf(fv) * c1[row * 256 + t] + sigf(iv) * tanhf(gv);
    float h2 = qg[row * 256 + t] + sigf(ov) * tanhf(cv);
    float nn = h2 * h2, dd = h2 * sgn[t];
    #pragma unroll
    for (int i = 32; i >= 1; i >>= 1) { nn += __shfl_xor(nn, i, 64); dd += __shfl_xor(dd, i, 64); }
    if (lane == 0) { rn[wave] = nn; rd[wave] = dd; }
    __syncthreads();
    if (t == 0) {
        float n2 = rn[0] + rn[1] + rn[2] + rn[3];
        float dt = rd[0] + rd[1] + rd[2] + rd[3];
        outv[row] = dt / fmaxf(sqrtf(n2), 1e-12f);
    }
}

extern "C" void kernel_launch(void* const* d_in, const int* in_sizes, int n_in,
                              void* d_out, int out_size, void* d_ws, size_t ws_size,
                              hipStream_t stream)
{
    const int*   query    = (const int*)d_in[0];
    const int*   support  = (const int*)d_in[1];
    const int*   q_l_conn = (const int*)d_in[2];
    const int*   q_r_conn = (const int*)d_in[4];
    const int*   s_l_conn = (const int*)d_in[6];
    const int*   s_r_conn = (const int*)d_in[8];
    const float* emb      = (const float*)d_in[10];
    const float* gcn_W    = (const float*)d_in[11];
    const float* gcn_bias = (const float*)d_in[12];
    const float* gcn_b    = (const float*)d_in[13];
    const float* se_w1    = (const float*)d_in[14];
    const float* se_b1    = (const float*)d_in[15];
    const float* se_w2    = (const float*)d_in[16];
    const float* se_b2    = (const float*)d_in[17];
    const float* ln_g     = (const float*)d_in[18];
    const float* ln_b     = (const float*)d_in[19];
    const float* W_ih     = (const float*)d_in[20];
    const float* W_hh     = (const float*)d_in[21];
    const float* b_ih     = (const float*)d_in[22];
    const float* b_hh     = (const float*)d_in[23];
    float* out = (float*)d_out;

    float* ws    = (float*)d_ws;
    float* qn2   = ws;                    // 1088*256
    float* h1q   = qn2   + 1088 * 256;    // 1088*512
    float* yq    = h1q   + 1088 * 512;    // 1088*256
    float* qg2   = yq    + 1088 * 256;    // 1088*256
    float* sg0   = qg2   + 1088 * 256;    // 256
    float* sgn   = sg0   + 256;           // 256
    float* bsum  = sgn   + 256;           // 2048
    float* gates = bsum  + 2048;          // 1024*1024
    float* c1    = gates + 1024 * 1024;   // 1024*256
    float* hr    = c1    + 1024 * 256;    // 1024*512

    // 1. neighbor encoder -> qn2 rows [0,1024)=query, [1024,1029)=support
    neighbor_kernel<<<2 * BB + 2 * FEW, 256, 0, stream>>>(
        query, support, q_l_conn, q_r_conn, s_l_conn, s_r_conn,
        emb, gcn_W, gcn_bias, gcn_b, qn2);

    // 2. bias precompute for LSTM gates
    bsum_kernel<<<8, 256, 0, stream>>>(b_ih, b_hh, bsum);

    // 3. SE MLP (query + support rows folded together, M=1088)
    gemm_nt<true, false, false><<<dim3(8, 17), 256, 0, stream>>>(
        qn2, se_w1, se_b1, nullptr, h1q, 1088, 512, 256);
    gemm_nt<false, true, false><<<dim3(4, 17), 256, 0, stream>>>(
        h1q, se_w2, se_b2, qn2, yq, 1088, 256, 512);
    ln_kernel<<<1029, 256, 0, stream>>>(yq, ln_g, ln_b, qg2);

    // 4. support_g mean + l2norm
    support_mean_kernel<<<1, 256, 0, stream>>>(qg2, sg0, sgn);

    // 5. gates_base = qg @ W_ih'^T + (b_ih+b_hh)   (gate-compacted N=1024)
    gemm_nt<false, false, true><<<dim3(16, 16), 256, 0, stream>>>(
        qg2, W_ih, bsum, nullptr, gates, 1024, 1024, 256);

    // 6. LSTM step 1 (c0=0, h_r0=0 => gates==gates_base)
    lstm_step1_kernel<<<1024, 256, 0, stream>>>(gates, qg2, sg0, c1, hr);

    // 7. gates2 = gates_base + hr @ W_hh'^T   (in-place add)
    gemm_nt<false, true, true><<<dim3(16, 16), 256, 0, stream>>>(
        hr, W_hh, nullptr, gates, gates, 1024, 1024, 512);

    // 8. LSTM step 2 + l2norm + dot(support_gn)
    lstm_step2_kernel<<<1024, 256, 0, stream>>>(gates, c1, qg2, sgn, out);
}